// Round 2
// baseline (1102.231 us; speedup 1.0000x reference)
//
#include <hip/hip_runtime.h>

typedef unsigned int uint;
typedef unsigned short ushort_t;

// Problem constants
constexpr int Bsz = 4096, NX = 64, NU = 16, NXU = 80, HID = 256, Hh = 50;
constexpr long NS = (long)Bsz * Hh * NU;   // noise per-iteration stride: 3,276,800
// Output offsets (floats), concatenated in return order
constexpr int O1 = 65536;                  // x_traj  (B,51,64)
constexpr int O2 = 13434880;               // pred    (B,50,64)
constexpr int O3 = 26542080;               // gx      (B,50,64)
constexpr int O4 = 39649280;               // gu      (B,50,16)
constexpr int XT_PITCH = (Hh + 1) * NX;    // 3264
constexpr int PR_PITCH = Hh * NX;          // 3200
constexpr int U_PITCH = Hh * NU;           // 800

// LDS strides (padded)
constexpr int W1S = 260;   // W1L row stride (floats)
constexpr int HS  = 264;   // hRT row stride (floats)
constexpr int TS  = 264;   // tT row stride (shorts) -> 132 uints
constexpr int W2S = 264;   // W2T row stride (shorts) -> 132 uints

__device__ __forceinline__ float tanh_fast(float x) {
    float e = __expf(2.0f * x);
    return 1.0f - 2.0f / (e + 1.0f);   // safe at +/-inf
}
__device__ __forceinline__ uint f2bf_u(float x) {
    uint b = __float_as_uint(x);
    return (b + 0x7FFFu + ((b >> 16) & 1u)) >> 16;   // RNE, low 16 bits valid
}
__device__ __forceinline__ float bf2f(ushort_t u) {
    return __uint_as_float(((uint)u) << 16);
}
__device__ __forceinline__ void unpack8(uint4 v, float* f) {
    f[0] = __uint_as_float(v.x << 16); f[1] = __uint_as_float(v.x & 0xFFFF0000u);
    f[2] = __uint_as_float(v.y << 16); f[3] = __uint_as_float(v.y & 0xFFFF0000u);
    f[4] = __uint_as_float(v.z << 16); f[5] = __uint_as_float(v.z & 0xFFFF0000u);
    f[6] = __uint_as_float(v.w << 16); f[7] = __uint_as_float(v.w & 0xFFFF0000u);
}

// One fused kernel: rollout + per-step linearization + control outputs.
// Reads ONLY d_in; writes every d_out element exactly once; no d_ws.
__global__ __launch_bounds__(256) void ker_fused(const float* __restrict__ x0,
                                                 const float* __restrict__ W1,
                                                 const float* __restrict__ b1,
                                                 const float* __restrict__ W2,
                                                 const float* __restrict__ noise,
                                                 const int* __restrict__ nit_p,
                                                 float* __restrict__ out) {
    __shared__ __align__(16) float    W1L[NXU * W1S];   // [80][260] fp32  83,200 B
    __shared__ __align__(16) ushort_t W2T[NX * W2S];    // [64][264] bf16  33,792 B
    __shared__ __align__(16) float    hRT[16 * HS];     // [16][264] fp32  16,896 B
    __shared__ __align__(16) ushort_t tT[16 * TS];      // [16][264] bf16   8,448 B
    __shared__ __align__(16) float    zT[NXU * 16];     // [80][16]  fp32   5,120 B
    __shared__ float b1L[HID];                          //                  1,024 B
    __shared__ float sL[HID];                           //                  1,024 B
    // total: 149,504 B (< 160 KiB)

    const int tid = threadIdx.x;
    const int b0 = blockIdx.x * 16;
    const int nit = nit_p[0];

    // ---- staging ----
    for (int i = tid; i < NXU * HID; i += 256)
        W1L[(i >> 8) * W1S + (i & 255)] = W1[i];
    for (int i = tid; i < HID * NX; i += 256) {         // W2[c][d] -> W2T[d][c] bf16
        int c = i >> 6, d = i & 63;
        W2T[d * W2S + c] = (ushort_t)f2bf_u(W2[i]);
    }
    b1L[tid] = b1[tid];
    // zT x-rows + x_traj[:,0,:]
    for (int i = tid; i < 16 * NX; i += 256) {
        int r = i >> 6, d = i & 63;
        float v = x0[(b0 + r) * NX + d];
        zT[d * 16 + r] = v;
        out[O1 + (b0 + r) * XT_PITCH + d] = v;
    }
    // step-0 controls (u9) + output 0 (first controls of u10)
    const int r16 = tid >> 4, q16 = tid & 15;
    {
        long base = (long)(b0 + r16) * U_PITCH + q16;
        float s = 0.f;
        for (int it = 0; it < nit - 1; ++it) s += noise[(long)it * NS + base];
        zT[(NX + q16) * 16 + r16] = 0.001f * s;
        out[(b0 + r16) * NU + q16] = 0.001f * (s + noise[(long)(nit - 1) * NS + base]);
    }
    __syncthreads();
    // sL[j] = 0.1 * rowsum(W2)[j]  (from staged bf16 W2T: column j, all d)
    {
        float s = 0.f;
        for (int d = 0; d < NX; ++d) s += bf2f(W2T[d * W2S + tid]);
        sL[tid] = 0.1f * s;
    }

    const int ct = tid & 63, rt = tid >> 6;   // P1 mapping: cols 4ct..+3, rows 4rt..+3
    uint* tTu = (uint*)tT;
    const uint* W2Tu = (const uint*)W2T;

    for (int k = 0; k < Hh; ++k) {
        __syncthreads();   // zT/tT/hRT/sL ready for this iteration

        // ---- issue next-step u loads early (latency hidden under P1) ----
        float v9[9];
        const bool fast = (k < Hh - 1) && (nit == 10);
        long nbase = (long)(b0 + r16) * U_PITCH + (k + 1) * NU + q16;
        if (fast) {
            #pragma unroll
            for (int it = 0; it < 9; ++it) v9[it] = noise[(long)it * NS + nbase];
        }

        // ---- P1: a = z@W1 + b1 ; h = tanh(a) -> hRT ; t = s*(1-h^2) -> tT ----
        float a_[4][4];
        {
            float bj[4];
            #pragma unroll
            for (int j = 0; j < 4; ++j) bj[j] = b1L[4 * ct + j];
            #pragma unroll
            for (int i = 0; i < 4; ++i)
                #pragma unroll
                for (int j = 0; j < 4; ++j) a_[i][j] = bj[j];
        }
        #pragma unroll 8
        for (int kk = 0; kk < NXU; ++kk) {
            float4 zv = *(const float4*)&zT[kk * 16 + 4 * rt];
            float4 wv = *(const float4*)&W1L[kk * W1S + 4 * ct];
            float zz[4] = {zv.x, zv.y, zv.z, zv.w};
            float ww[4] = {wv.x, wv.y, wv.z, wv.w};
            #pragma unroll
            for (int i = 0; i < 4; ++i)
                #pragma unroll
                for (int j = 0; j < 4; ++j) a_[i][j] += zz[i] * ww[j];
        }
        float h_[4][4];
        #pragma unroll
        for (int i = 0; i < 4; ++i)
            #pragma unroll
            for (int j = 0; j < 4; ++j) h_[i][j] = tanh_fast(a_[i][j]);
        #pragma unroll
        for (int i = 0; i < 4; ++i)
            *(float4*)&hRT[(4 * rt + i) * HS + 4 * ct] =
                make_float4(h_[i][0], h_[i][1], h_[i][2], h_[i][3]);
        {
            float s0 = sL[4 * ct], s1 = sL[4 * ct + 1], s2 = sL[4 * ct + 2], s3 = sL[4 * ct + 3];
            #pragma unroll
            for (int i = 0; i < 4; ++i) {
                float t0 = s0 * (1.f - h_[i][0] * h_[i][0]);
                float t1 = s1 * (1.f - h_[i][1] * h_[i][1]);
                float t2 = s2 * (1.f - h_[i][2] * h_[i][2]);
                float t3 = s3 * (1.f - h_[i][3] * h_[i][3]);
                tTu[(4 * rt + i) * (TS / 2) + 2 * ct]     = f2bf_u(t0) | (f2bf_u(t1) << 16);
                tTu[(4 * rt + i) * (TS / 2) + 2 * ct + 1] = f2bf_u(t2) | (f2bf_u(t3) << 16);
            }
        }

        // ---- finish u prefetch sum (loads already in flight) ----
        float unext = 0.f;
        if (k < Hh - 1) {
            if (fast) {
                #pragma unroll
                for (int it = 0; it < 9; ++it) unext += v9[it];
            } else {
                for (int it = 0; it < nit - 1; ++it) unext += noise[(long)it * NS + nbase];
            }
            unext *= 0.001f;
        }

        __syncthreads();   // hRT/tT visible; zT u-rows free to overwrite

        // ---- P2: x_next = x + 0.1*h@W2 ; thread r16, cols d = q16+16*i ----
        float xacc[4] = {0.f, 0.f, 0.f, 0.f};
        #pragma unroll 4
        for (int c8 = 0; c8 < HID / 8; ++c8) {
            float4 h0 = *(const float4*)&hRT[r16 * HS + 8 * c8];
            float4 h1 = *(const float4*)&hRT[r16 * HS + 8 * c8 + 4];
            float hf[8] = {h0.x, h0.y, h0.z, h0.w, h1.x, h1.y, h1.z, h1.w};
            #pragma unroll
            for (int i = 0; i < 4; ++i) {
                int d = q16 + 16 * i;
                uint4 wv = *(const uint4*)&W2Tu[d * (W2S / 2) + 4 * c8];
                float wf[8];
                unpack8(wv, wf);
                #pragma unroll
                for (int jj = 0; jj < 8; ++jj) xacc[i] += hf[jj] * wf[jj];
            }
        }
        {
            const int bb = b0 + r16;
            #pragma unroll
            for (int i = 0; i < 4; ++i) {
                int d = q16 + 16 * i;
                float xn = zT[d * 16 + r16] + 0.1f * xacc[i];
                out[O1 + bb * XT_PITCH + (k + 1) * NX + d] = xn;
                out[O2 + bb * PR_PITCH + k * NX + d] = xn;
                zT[d * 16 + r16] = xn;
            }
            if (k < Hh - 1) zT[(NX + q16) * 16 + r16] = unext;
        }

        // ---- C: g = t @ W1^T ; thread r16, outputs p = q16+16*i (i<5) ----
        {
            const uint* tTr = (const uint*)tT + r16 * (TS / 2);
            float g_[5] = {0.f, 0.f, 0.f, 0.f, 0.f};
            #pragma unroll 4
            for (int jc = 0; jc < HID / 8; ++jc) {
                uint4 tv = *(const uint4*)&tTr[4 * jc];
                float tf[8];
                unpack8(tv, tf);
                #pragma unroll
                for (int i = 0; i < 5; ++i) {
                    int p = q16 + 16 * i;
                    float4 w0 = *(const float4*)&W1L[p * W1S + 8 * jc];
                    float4 w1 = *(const float4*)&W1L[p * W1S + 8 * jc + 4];
                    g_[i] += tf[0] * w0.x + tf[1] * w0.y + tf[2] * w0.z + tf[3] * w0.w
                           + tf[4] * w1.x + tf[5] * w1.y + tf[6] * w1.z + tf[7] * w1.w;
                }
            }
            const int bb = b0 + r16;
            #pragma unroll
            for (int i = 0; i < 4; ++i)
                out[O3 + bb * PR_PITCH + k * NX + (q16 + 16 * i)] = 1.0f + g_[i];
            out[O4 + bb * U_PITCH + k * NU + q16] = g_[4];
        }
    }
}

extern "C" void kernel_launch(void* const* d_in, const int* in_sizes, int n_in,
                              void* d_out, int out_size, void* d_ws, size_t ws_size,
                              hipStream_t stream) {
    const float* x0    = (const float*)d_in[0];
    // d_in[1] = xref (unused)
    const float* W1    = (const float*)d_in[2];
    const float* b1    = (const float*)d_in[3];
    const float* W2    = (const float*)d_in[4];
    const float* noise = (const float*)d_in[5];
    const int*   nit   = (const int*)d_in[6];
    float* out = (float*)d_out;

    ker_fused<<<Bsz / 16, 256, 0, stream>>>(x0, W1, b1, W2, noise, nit, out);
}

// Round 3
// 790.698 us; speedup vs baseline: 1.3940x; 1.3940x over previous
//
#include <hip/hip_runtime.h>

typedef unsigned int uint;
typedef unsigned short ushort_t;
typedef __attribute__((ext_vector_type(8))) short bf16x8_t;   // 8 bf16 (4 VGPRs)
typedef __attribute__((ext_vector_type(4))) float f32x4_t;    // MFMA acc

// Problem constants
constexpr int Bsz = 4096, NX = 64, NU = 16, NXU = 80, HID = 256, Hh = 50;
constexpr long NS = (long)Bsz * Hh * NU;   // noise per-iteration stride: 3,276,800
// Output offsets (floats), concatenated in return order
constexpr int O1 = 65536;                  // x_traj  (B,51,64)
constexpr int O2 = 13434880;               // pred    (B,50,64)
constexpr int O3 = 26542080;               // gx      (B,50,64)
constexpr int O4 = 39649280;               // gu      (B,50,16)
constexpr int XT_PITCH = (Hh + 1) * NX;    // 3264
constexpr int PR_PITCH = Hh * NX;          // 3200
constexpr int U_PITCH = Hh * NU;           // 800

// LDS strides (padded)
constexpr int W1S = 260;   // W1L row stride (floats)
constexpr int HS  = 264;   // hRT row stride (floats)
constexpr int TS  = 264;   // tT row stride (shorts)  (fallback kernel only)
constexpr int W2S = 264;   // W2T row stride (shorts)
constexpr int TLS = 264;   // K2 LDS row stride (shorts); 264*2=528 B, 16B-aligned

constexpr long T_BYTES = (long)Bsz * Hh * HID * 2;   // 104,857,600 B in d_ws

__device__ __forceinline__ float tanh_fast(float x) {
    float e = __expf(2.0f * x);
    return 1.0f - 2.0f / (e + 1.0f);   // safe at +/-inf
}
__device__ __forceinline__ uint f2bf_u(float x) {
    uint b = __float_as_uint(x);
    return (b + 0x7FFFu + ((b >> 16) & 1u)) >> 16;   // RNE, low 16 bits valid
}
__device__ __forceinline__ float bf2f(ushort_t u) {
    return __uint_as_float(((uint)u) << 16);
}
__device__ __forceinline__ void unpack8(uint4 v, float* f) {
    f[0] = __uint_as_float(v.x << 16); f[1] = __uint_as_float(v.x & 0xFFFF0000u);
    f[2] = __uint_as_float(v.y << 16); f[3] = __uint_as_float(v.y & 0xFFFF0000u);
    f[4] = __uint_as_float(v.z << 16); f[5] = __uint_as_float(v.z & 0xFFFF0000u);
    f[6] = __uint_as_float(v.w << 16); f[7] = __uint_as_float(v.w & 0xFFFF0000u);
}

// =====================================================================
// K1: sequential rollout (P1+P2), 16 batch rows/block, 256 blocks.
// Streams t = s*(1-h^2) (bf16) to d_ws for K2. No linearization here.
// =====================================================================
__global__ __launch_bounds__(256) void ker_roll(const float* __restrict__ x0,
                                                const float* __restrict__ W1,
                                                const float* __restrict__ b1,
                                                const float* __restrict__ W2,
                                                const float* __restrict__ noise,
                                                const int* __restrict__ nit_p,
                                                float* __restrict__ out,
                                                ushort_t* __restrict__ tg) {
    __shared__ __align__(16) float    W1L[NXU * W1S];   // 83,200 B
    __shared__ __align__(16) ushort_t W2T[NX * W2S];    // 33,792 B
    __shared__ __align__(16) float    hRT[16 * HS];     // 16,896 B
    __shared__ __align__(16) float    zT[NXU * 16];     //  5,120 B
    __shared__ float b1L[HID];                          //  1,024 B
    __shared__ float sL[HID];                           //  1,024 B
    // total 141,056 B

    const int tid = threadIdx.x;
    const int b0 = blockIdx.x * 16;
    const int nit = nit_p[0];

    for (int i = tid; i < NXU * HID; i += 256)
        W1L[(i >> 8) * W1S + (i & 255)] = W1[i];
    for (int i = tid; i < HID * NX; i += 256) {
        int c = i >> 6, d = i & 63;
        W2T[d * W2S + c] = (ushort_t)f2bf_u(W2[i]);
    }
    b1L[tid] = b1[tid];
    for (int i = tid; i < 16 * NX; i += 256) {
        int r = i >> 6, d = i & 63;
        float v = x0[(b0 + r) * NX + d];
        zT[d * 16 + r] = v;
        out[O1 + (b0 + r) * XT_PITCH + d] = v;
    }
    const int r16 = tid >> 4, q16 = tid & 15;
    {
        long base = (long)(b0 + r16) * U_PITCH + q16;
        float s = 0.f;
        for (int it = 0; it < nit - 1; ++it) s += noise[(long)it * NS + base];
        zT[(NX + q16) * 16 + r16] = 0.001f * s;
        out[(b0 + r16) * NU + q16] = 0.001f * (s + noise[(long)(nit - 1) * NS + base]);
    }
    __syncthreads();
    {
        float s = 0.f;
        for (int d = 0; d < NX; ++d) s += bf2f(W2T[d * W2S + tid]);
        sL[tid] = 0.1f * s;
    }

    const int ct = tid & 63, rt = tid >> 6;
    const uint* W2Tu = (const uint*)W2T;

    for (int k = 0; k < Hh; ++k) {
        __syncthreads();

        // prefetch next-step controls
        float v9[9];
        const bool fast = (k < Hh - 1) && (nit == 10);
        long nbase = (long)(b0 + r16) * U_PITCH + (k + 1) * NU + q16;
        if (fast) {
            #pragma unroll
            for (int it = 0; it < 9; ++it) v9[it] = noise[(long)it * NS + nbase];
        }

        // ---- P1: a = z@W1 + b1 ; h -> hRT ; t -> global (d_ws) ----
        float a_[4][4];
        {
            float bj[4];
            #pragma unroll
            for (int j = 0; j < 4; ++j) bj[j] = b1L[4 * ct + j];
            #pragma unroll
            for (int i = 0; i < 4; ++i)
                #pragma unroll
                for (int j = 0; j < 4; ++j) a_[i][j] = bj[j];
        }
        #pragma unroll 8
        for (int kk = 0; kk < NXU; ++kk) {
            float4 zv = *(const float4*)&zT[kk * 16 + 4 * rt];
            float4 wv = *(const float4*)&W1L[kk * W1S + 4 * ct];
            float zz[4] = {zv.x, zv.y, zv.z, zv.w};
            float ww[4] = {wv.x, wv.y, wv.z, wv.w};
            #pragma unroll
            for (int i = 0; i < 4; ++i)
                #pragma unroll
                for (int j = 0; j < 4; ++j) a_[i][j] += zz[i] * ww[j];
        }
        float h_[4][4];
        #pragma unroll
        for (int i = 0; i < 4; ++i)
            #pragma unroll
            for (int j = 0; j < 4; ++j) h_[i][j] = tanh_fast(a_[i][j]);
        #pragma unroll
        for (int i = 0; i < 4; ++i)
            *(float4*)&hRT[(4 * rt + i) * HS + 4 * ct] =
                make_float4(h_[i][0], h_[i][1], h_[i][2], h_[i][3]);
        {
            float s0 = sL[4 * ct], s1 = sL[4 * ct + 1], s2 = sL[4 * ct + 2], s3 = sL[4 * ct + 3];
            #pragma unroll
            for (int i = 0; i < 4; ++i) {
                float t0 = s0 * (1.f - h_[i][0] * h_[i][0]);
                float t1 = s1 * (1.f - h_[i][1] * h_[i][1]);
                float t2 = s2 * (1.f - h_[i][2] * h_[i][2]);
                float t3 = s3 * (1.f - h_[i][3] * h_[i][3]);
                size_t rho = (size_t)(b0 + 4 * rt + i) * Hh + k;
                uint2 pk = make_uint2(f2bf_u(t0) | (f2bf_u(t1) << 16),
                                      f2bf_u(t2) | (f2bf_u(t3) << 16));
                *(uint2*)(tg + rho * HID + 4 * ct) = pk;   // coalesced 512 B/row
            }
        }

        float unext = 0.f;
        if (k < Hh - 1) {
            if (fast) {
                #pragma unroll
                for (int it = 0; it < 9; ++it) unext += v9[it];
            } else {
                for (int it = 0; it < nit - 1; ++it) unext += noise[(long)it * NS + nbase];
            }
            unext *= 0.001f;
        }

        __syncthreads();

        // ---- P2: x_next = x + 0.1*h@W2 ----
        float xacc[4] = {0.f, 0.f, 0.f, 0.f};
        #pragma unroll 4
        for (int c8 = 0; c8 < HID / 8; ++c8) {
            float4 h0 = *(const float4*)&hRT[r16 * HS + 8 * c8];
            float4 h1 = *(const float4*)&hRT[r16 * HS + 8 * c8 + 4];
            float hf[8] = {h0.x, h0.y, h0.z, h0.w, h1.x, h1.y, h1.z, h1.w};
            #pragma unroll
            for (int i = 0; i < 4; ++i) {
                int d = q16 + 16 * i;
                uint4 wv = *(const uint4*)&W2Tu[d * (W2S / 2) + 4 * c8];
                float wf[8];
                unpack8(wv, wf);
                #pragma unroll
                for (int jj = 0; jj < 8; ++jj) xacc[i] += hf[jj] * wf[jj];
            }
        }
        {
            const int bb = b0 + r16;
            #pragma unroll
            for (int i = 0; i < 4; ++i) {
                int d = q16 + 16 * i;
                float xn = zT[d * 16 + r16] + 0.1f * xacc[i];
                out[O1 + bb * XT_PITCH + (k + 1) * NX + d] = xn;
                out[O2 + bb * PR_PITCH + k * NX + d] = xn;
                zT[d * 16 + r16] = xn;
            }
            if (k < Hh - 1) zT[(NX + q16) * 16 + r16] = unext;
        }
    }
}

// =====================================================================
// K2: G[204800 x 80] = T[204800 x 256] @ W1^T, bf16 MFMA 16x16x32.
// gx = 1 + G[:, :64], gu = G[:, 64:80]. 1600 blocks x 128 rows.
// =====================================================================
__global__ __launch_bounds__(256) void ker_lin2(const float* __restrict__ W1,
                                                const ushort_t* __restrict__ Tg,
                                                float* __restrict__ out) {
    __shared__ __align__(16) ushort_t Tl[128 * TLS];    // 67,584 B
    __shared__ __align__(16) ushort_t W1b[NXU * TLS];   // 42,240 B

    const int tid = threadIdx.x;
    const int r0 = blockIdx.x * 128;

    for (int i = tid; i < NXU * HID; i += 256) {
        int p = i >> 8, c = i & 255;
        W1b[p * TLS + c] = (ushort_t)f2bf_u(W1[i]);
    }
    {   // stage 128 rows x 512 B of T, fully coalesced
        const uint4* Tg4 = (const uint4*)(Tg + (size_t)r0 * HID);
        for (int i = tid; i < 128 * 32; i += 256) {
            int r = i >> 5, c8 = i & 31;
            *(uint4*)&Tl[r * TLS + c8 * 8] = Tg4[i];
        }
    }
    __syncthreads();

    const int wv = tid >> 6, lane = tid & 63;
    const int m = lane & 15, quad = lane >> 4;

    f32x4_t acc[2][5];
    #pragma unroll
    for (int i = 0; i < 2; ++i)
        #pragma unroll
        for (int j = 0; j < 5; ++j) acc[i][j] = (f32x4_t){0.f, 0.f, 0.f, 0.f};

    #pragma unroll
    for (int kc = 0; kc < 8; ++kc) {
        const int koff = kc * 32 + quad * 8;
        bf16x8_t a0 = *(const bf16x8_t*)&Tl[(wv * 32 + m) * TLS + koff];
        bf16x8_t a1 = *(const bf16x8_t*)&Tl[(wv * 32 + 16 + m) * TLS + koff];
        #pragma unroll
        for (int nt = 0; nt < 5; ++nt) {
            bf16x8_t bfr = *(const bf16x8_t*)&W1b[(nt * 16 + m) * TLS + koff];
            acc[0][nt] = __builtin_amdgcn_mfma_f32_16x16x32_bf16(a0, bfr, acc[0][nt], 0, 0, 0);
            acc[1][nt] = __builtin_amdgcn_mfma_f32_16x16x32_bf16(a1, bfr, acc[1][nt], 0, 0, 0);
        }
    }

    // Epilogue: C/D layout col=lane&15, row=quad*4+reg
    #pragma unroll
    for (int mt = 0; mt < 2; ++mt) {
        int rbase = r0 + wv * 32 + mt * 16 + quad * 4;
        #pragma unroll
        for (int r = 0; r < 4; ++r) {
            int rho = rbase + r;
            int b = (int)(((unsigned long long)rho * 1374389535ULL) >> 36);  // rho/50
            int kk = rho - b * 50;
            float* gxp = out + O3 + (size_t)b * PR_PITCH + kk * NX + m;
            #pragma unroll
            for (int nt = 0; nt < 4; ++nt)
                gxp[nt * 16] = 1.0f + acc[mt][nt][r];
            out[O4 + (size_t)b * U_PITCH + kk * NU + m] = acc[mt][4][r];
        }
    }
}

// =====================================================================
// Fallback: R2's proven fused kernel (used only if ws_size is too small)
// =====================================================================
__global__ __launch_bounds__(256) void ker_fused(const float* __restrict__ x0,
                                                 const float* __restrict__ W1,
                                                 const float* __restrict__ b1,
                                                 const float* __restrict__ W2,
                                                 const float* __restrict__ noise,
                                                 const int* __restrict__ nit_p,
                                                 float* __restrict__ out) {
    __shared__ __align__(16) float    W1L[NXU * W1S];
    __shared__ __align__(16) ushort_t W2T[NX * W2S];
    __shared__ __align__(16) float    hRT[16 * HS];
    __shared__ __align__(16) ushort_t tT[16 * TS];
    __shared__ __align__(16) float    zT[NXU * 16];
    __shared__ float b1L[HID];
    __shared__ float sL[HID];

    const int tid = threadIdx.x;
    const int b0 = blockIdx.x * 16;
    const int nit = nit_p[0];

    for (int i = tid; i < NXU * HID; i += 256)
        W1L[(i >> 8) * W1S + (i & 255)] = W1[i];
    for (int i = tid; i < HID * NX; i += 256) {
        int c = i >> 6, d = i & 63;
        W2T[d * W2S + c] = (ushort_t)f2bf_u(W2[i]);
    }
    b1L[tid] = b1[tid];
    for (int i = tid; i < 16 * NX; i += 256) {
        int r = i >> 6, d = i & 63;
        float v = x0[(b0 + r) * NX + d];
        zT[d * 16 + r] = v;
        out[O1 + (b0 + r) * XT_PITCH + d] = v;
    }
    const int r16 = tid >> 4, q16 = tid & 15;
    {
        long base = (long)(b0 + r16) * U_PITCH + q16;
        float s = 0.f;
        for (int it = 0; it < nit - 1; ++it) s += noise[(long)it * NS + base];
        zT[(NX + q16) * 16 + r16] = 0.001f * s;
        out[(b0 + r16) * NU + q16] = 0.001f * (s + noise[(long)(nit - 1) * NS + base]);
    }
    __syncthreads();
    {
        float s = 0.f;
        for (int d = 0; d < NX; ++d) s += bf2f(W2T[d * W2S + tid]);
        sL[tid] = 0.1f * s;
    }

    const int ct = tid & 63, rt = tid >> 6;
    uint* tTu = (uint*)tT;
    const uint* W2Tu = (const uint*)W2T;

    for (int k = 0; k < Hh; ++k) {
        __syncthreads();
        float v9[9];
        const bool fast = (k < Hh - 1) && (nit == 10);
        long nbase = (long)(b0 + r16) * U_PITCH + (k + 1) * NU + q16;
        if (fast) {
            #pragma unroll
            for (int it = 0; it < 9; ++it) v9[it] = noise[(long)it * NS + nbase];
        }
        float a_[4][4];
        {
            float bj[4];
            #pragma unroll
            for (int j = 0; j < 4; ++j) bj[j] = b1L[4 * ct + j];
            #pragma unroll
            for (int i = 0; i < 4; ++i)
                #pragma unroll
                for (int j = 0; j < 4; ++j) a_[i][j] = bj[j];
        }
        #pragma unroll 8
        for (int kk = 0; kk < NXU; ++kk) {
            float4 zv = *(const float4*)&zT[kk * 16 + 4 * rt];
            float4 wv = *(const float4*)&W1L[kk * W1S + 4 * ct];
            float zz[4] = {zv.x, zv.y, zv.z, zv.w};
            float ww[4] = {wv.x, wv.y, wv.z, wv.w};
            #pragma unroll
            for (int i = 0; i < 4; ++i)
                #pragma unroll
                for (int j = 0; j < 4; ++j) a_[i][j] += zz[i] * ww[j];
        }
        float h_[4][4];
        #pragma unroll
        for (int i = 0; i < 4; ++i)
            #pragma unroll
            for (int j = 0; j < 4; ++j) h_[i][j] = tanh_fast(a_[i][j]);
        #pragma unroll
        for (int i = 0; i < 4; ++i)
            *(float4*)&hRT[(4 * rt + i) * HS + 4 * ct] =
                make_float4(h_[i][0], h_[i][1], h_[i][2], h_[i][3]);
        {
            float s0 = sL[4 * ct], s1 = sL[4 * ct + 1], s2 = sL[4 * ct + 2], s3 = sL[4 * ct + 3];
            #pragma unroll
            for (int i = 0; i < 4; ++i) {
                float t0 = s0 * (1.f - h_[i][0] * h_[i][0]);
                float t1 = s1 * (1.f - h_[i][1] * h_[i][1]);
                float t2 = s2 * (1.f - h_[i][2] * h_[i][2]);
                float t3 = s3 * (1.f - h_[i][3] * h_[i][3]);
                tTu[(4 * rt + i) * (TS / 2) + 2 * ct]     = f2bf_u(t0) | (f2bf_u(t1) << 16);
                tTu[(4 * rt + i) * (TS / 2) + 2 * ct + 1] = f2bf_u(t2) | (f2bf_u(t3) << 16);
            }
        }
        float unext = 0.f;
        if (k < Hh - 1) {
            if (fast) {
                #pragma unroll
                for (int it = 0; it < 9; ++it) unext += v9[it];
            } else {
                for (int it = 0; it < nit - 1; ++it) unext += noise[(long)it * NS + nbase];
            }
            unext *= 0.001f;
        }
        __syncthreads();
        float xacc[4] = {0.f, 0.f, 0.f, 0.f};
        #pragma unroll 4
        for (int c8 = 0; c8 < HID / 8; ++c8) {
            float4 h0 = *(const float4*)&hRT[r16 * HS + 8 * c8];
            float4 h1 = *(const float4*)&hRT[r16 * HS + 8 * c8 + 4];
            float hf[8] = {h0.x, h0.y, h0.z, h0.w, h1.x, h1.y, h1.z, h1.w};
            #pragma unroll
            for (int i = 0; i < 4; ++i) {
                int d = q16 + 16 * i;
                uint4 wv = *(const uint4*)&W2Tu[d * (W2S / 2) + 4 * c8];
                float wf[8];
                unpack8(wv, wf);
                #pragma unroll
                for (int jj = 0; jj < 8; ++jj) xacc[i] += hf[jj] * wf[jj];
            }
        }
        {
            const int bb = b0 + r16;
            #pragma unroll
            for (int i = 0; i < 4; ++i) {
                int d = q16 + 16 * i;
                float xn = zT[d * 16 + r16] + 0.1f * xacc[i];
                out[O1 + bb * XT_PITCH + (k + 1) * NX + d] = xn;
                out[O2 + bb * PR_PITCH + k * NX + d] = xn;
                zT[d * 16 + r16] = xn;
            }
            if (k < Hh - 1) zT[(NX + q16) * 16 + r16] = unext;
        }
        {
            const uint* tTr = (const uint*)tT + r16 * (TS / 2);
            float g_[5] = {0.f, 0.f, 0.f, 0.f, 0.f};
            #pragma unroll 4
            for (int jc = 0; jc < HID / 8; ++jc) {
                uint4 tv = *(const uint4*)&tTr[4 * jc];
                float tf[8];
                unpack8(tv, tf);
                #pragma unroll
                for (int i = 0; i < 5; ++i) {
                    int p = q16 + 16 * i;
                    float4 w0 = *(const float4*)&W1L[p * W1S + 8 * jc];
                    float4 w1 = *(const float4*)&W1L[p * W1S + 8 * jc + 4];
                    g_[i] += tf[0] * w0.x + tf[1] * w0.y + tf[2] * w0.z + tf[3] * w0.w
                           + tf[4] * w1.x + tf[5] * w1.y + tf[6] * w1.z + tf[7] * w1.w;
                }
            }
            const int bb = b0 + r16;
            #pragma unroll
            for (int i = 0; i < 4; ++i)
                out[O3 + bb * PR_PITCH + k * NX + (q16 + 16 * i)] = 1.0f + g_[i];
            out[O4 + bb * U_PITCH + k * NU + q16] = g_[4];
        }
    }
}

extern "C" void kernel_launch(void* const* d_in, const int* in_sizes, int n_in,
                              void* d_out, int out_size, void* d_ws, size_t ws_size,
                              hipStream_t stream) {
    const float* x0    = (const float*)d_in[0];
    // d_in[1] = xref (unused)
    const float* W1    = (const float*)d_in[2];
    const float* b1    = (const float*)d_in[3];
    const float* W2    = (const float*)d_in[4];
    const float* noise = (const float*)d_in[5];
    const int*   nit   = (const int*)d_in[6];
    float* out = (float*)d_out;

    if (ws_size >= (size_t)T_BYTES) {
        ushort_t* tg = (ushort_t*)d_ws;
        ker_roll<<<Bsz / 16, 256, 0, stream>>>(x0, W1, b1, W2, noise, nit, out, tg);
        ker_lin2<<<(Bsz * Hh) / 128, 256, 0, stream>>>(W1, tg, out);
    } else {
        ker_fused<<<Bsz / 16, 256, 0, stream>>>(x0, W1, b1, W2, noise, nit, out);
    }
}